// Round 7
// baseline (425.292 us; speedup 1.0000x reference)
//
#include <hip/hip_runtime.h>
#include <hip/hip_bf16.h>

// TransformerBlock: B=2, S=2048, D=1024, H=16, hd=64, C=1024
// External tensors f32; internal bf16 MFMA (f32 accum).
// R14: attn = R8 structure (76.5us proven; single-buffer KV, 2 syncthreads,
// 25.6KB LDS -> 4 blocks/CU) + two VALU cuts, both correctness-proven in R9:
//  (1) Q pre-scaled by hd^-0.5*log2(e) at RoPE; softmax = raw v_exp_f32
//      (builtin, NOT the exp2f libcall R9 used) -> saves 16 v_mul/iter.
//  (2) paired u32 P-stores with contraction-axis permutation baked into V's
//      blocked rows (PV invariant; col c <-> k=16*(c&1)+(c>>1), V row
//      sp=(sl&32)|((sl&15)<<1)|((sl>>4)&1)) -> 16 ds_write_b16 + 8 extracts
//      become 8 ds_write_b32.
// Pipeline lesson (R9/R12/R13, triple-measured): attn staging is TLP-hidden
// at 4 blocks/CU; do NOT spend LDS on KV double-buffering here.
// GEMM identical to R11 (3-buffer counted-vmcnt pipeline, no XCD swizzle).
// Workspace: 48 MB + 48 KB.
//
// Blocked layout (bf16, inner-dim K): for row r, col k:
//   idx = (r>>7)*128*K + (k>>3)*1024 + (r&127)*8 + (k&7)
// attn K per (b,h): idx = kb*4096 + (d>>3)*512 + (s&63)*8 + (d&7), kb=s>>6
// attn V per (b,h): PERMUTED rows sp = (s&32)|((s&15)<<1)|((s>>4)&1):
//   idx = kb*4096 + (sp>>3)*512 + d*8 + (sp&7)

typedef unsigned short u16;
typedef unsigned int   u32;
typedef __bf16 bf16x8 __attribute__((ext_vector_type(8)));
typedef float  f32x4  __attribute__((ext_vector_type(4)));

#define MFMA_BF16(a, b, c) __builtin_amdgcn_mfma_f32_16x16x32_bf16((a), (b), (c), 0, 0, 0)

__device__ __forceinline__ float b2f(u16 u) {
    union { u32 i; float f; } v; v.i = ((u32)u) << 16; return v.f;
}
__device__ __forceinline__ u16 f2b(float f) {
    union { u32 i; float f; } v; v.f = f;
    u32 i = v.i;
    return (u16)((i + 0x7FFFu + ((i >> 16) & 1u)) >> 16);  // RNE
}
// packed f32x2 -> bf16x2 (low = a, high = b)
__device__ __forceinline__ u32 pk2(float a, float b) {
#if __has_builtin(__builtin_amdgcn_cvt_pk_bf16_f32)
    typedef __bf16 bf16x2_t __attribute__((ext_vector_type(2)));
    union { bf16x2_t v; u32 u; } cv;
    cv.v = __builtin_amdgcn_cvt_pk_bf16_f32(a, b);
    return cv.u;
#else
    return (u32)f2b(a) | ((u32)f2b(b) << 16);
#endif
}
// raw v_exp_f32 (2^x), no libcall wrapper
__device__ __forceinline__ float exp2_raw(float x) {
#if __has_builtin(__builtin_amdgcn_exp2f)
    return __builtin_amdgcn_exp2f(x);
#else
    float r;
    __asm("v_exp_f32 %0, %1" : "=v"(r) : "v"(x));
    return r;
#endif
}
__device__ __forceinline__ float finz(float v) {
    return __builtin_isfinite(v) ? v : 0.0f;
}
__device__ __forceinline__ void dma16(const void* g, void* l) {
    __builtin_amdgcn_global_load_lds(
        (const __attribute__((address_space(1))) unsigned int*)(uintptr_t)g,
        (__attribute__((address_space(3))) unsigned int*)(uintptr_t)l,
        16, 0, 0);
}

// ---------------------------------------------------------------------------
// f32 -> bf16 blocked weight conversion. Thread i emits 8 contiguous u16 of
// the blocked output (one (row, kg) cell); reads 8 contiguous floats.
// ---------------------------------------------------------------------------
__global__ __launch_bounds__(256) void convert_kernel(
    const float* __restrict__ in, u16* __restrict__ out, int n8, int kshift)
{
    int i = blockIdx.x * 256 + threadIdx.x;
    if (i >= n8) return;
    size_t o = (size_t)i * 8;
    int bk   = (int)(o >> (kshift + 7));
    int rem  = (int)(o & (((size_t)128 << kshift) - 1));
    int kg   = rem >> 10;
    int nloc = (rem >> 3) & 127;
    const float* src = in + (((size_t)bk * 128 + nloc) << kshift) + kg * 8;
    float4 a = *(const float4*)src;
    float4 b = *(const float4*)(src + 4);
    union { u16 s[8]; float4 v; } wp;
    wp.s[0] = f2b(a.x); wp.s[1] = f2b(a.y); wp.s[2] = f2b(a.z); wp.s[3] = f2b(a.w);
    wp.s[4] = f2b(b.x); wp.s[5] = f2b(b.y); wp.s[6] = f2b(b.z); wp.s[7] = f2b(b.w);
    *(float4*)(out + o) = wp.v;
}

// ---------------------------------------------------------------------------
// mods = c @ ada_w.T + ada_b : (2, 6144), K=1024, f32. One wave per column.
// ---------------------------------------------------------------------------
__global__ __launch_bounds__(64) void mods_kernel(
    const float* __restrict__ c, const float* __restrict__ ada_w,
    const float* __restrict__ ada_b, float* __restrict__ mods)
{
    const int n = blockIdx.x;
    const int lane = threadIdx.x;
    const float* wr = ada_w + (size_t)n * 1024;
    float a0 = 0.f, a1 = 0.f;
    for (int k = lane; k < 1024; k += 64) {
        float w = wr[k];
        a0 += w * c[k];
        a1 += w * c[1024 + k];
    }
    for (int o = 32; o > 0; o >>= 1) {
        a0 += __shfl_down(a0, o, 64);
        a1 += __shfl_down(a1, o, 64);
    }
    if (lane == 0) {
        float bb = ada_b[n];
        mods[n]        = a0 + bb;
        mods[6144 + n] = a1 + bb;
    }
}

// ---------------------------------------------------------------------------
// LayerNorm + adaLN modulation. Input f32 (xf) or bf16 row-major (xbf).
// Output bf16 in BLOCKED layout (K=1024).
// ---------------------------------------------------------------------------
__global__ __launch_bounds__(256) void ln_mod_kernel(
    const u16* __restrict__ xbf, const float* __restrict__ xf,
    const float* __restrict__ w, const float* __restrict__ mods,
    int scale_off, int shift_off, u16* __restrict__ out)
{
    const int row = blockIdx.x;          // b*2048 + s
    const int b   = row >> 11;
    const int tid = threadIdx.x;
    const size_t base = (size_t)row * 1024 + tid * 4;
    float v[4];
    if (xf) {
        float4 t = *(const float4*)(xf + base);
        v[0] = t.x; v[1] = t.y; v[2] = t.z; v[3] = t.w;
    } else {
        uint2 p = *(const uint2*)(xbf + base);
        union { u32 i; float f; } a, bb, cc, d;
        a.i  = p.x << 16;          v[0] = a.f;
        bb.i = p.x & 0xFFFF0000u;  v[1] = bb.f;
        cc.i = p.y << 16;          v[2] = cc.f;
        d.i  = p.y & 0xFFFF0000u;  v[3] = d.f;
    }
    float s  = v[0] + v[1] + v[2] + v[3];
    float sq = v[0]*v[0] + v[1]*v[1] + v[2]*v[2] + v[3]*v[3];
    __shared__ float rs[256], rq[256];
    rs[tid] = s; rq[tid] = sq;
    __syncthreads();
    for (int o = 128; o > 0; o >>= 1) {
        if (tid < o) { rs[tid] += rs[tid + o]; rq[tid] += rq[tid + o]; }
        __syncthreads();
    }
    const float mean = rs[0] * (1.0f / 1024.0f);
    const float var  = rq[0] * (1.0f / 1024.0f) - mean * mean;
    const float inv  = rsqrtf(fmaxf(var, 0.f) + 1e-5f);
    union { u16 s4[4]; uint2 u2; } pk;
    for (int i = 0; i < 4; ++i) {
        int cidx = tid * 4 + i;
        float y = (v[i] - mean) * inv * w[cidx];
        y = y * (1.0f + mods[b * 6144 + scale_off + cidx]) + mods[b * 6144 + shift_off + cidx];
        pk.s4[i] = f2b(y);
    }
    size_t o = ((size_t)(row >> 7)) * 131072 + ((tid * 4) >> 3) * 1024
             + (row & 127) * 8 + ((tid * 4) & 7);
    *(uint2*)(out + o) = pk.u2;
}

// ---------------------------------------------------------------------------
// m97-style GEMM on BLOCKED operands: C[M,N] = A[M,K] @ W[N,K]^T.
// 128x128 tile, BK=32, 4 waves (2x2), 4x4 16x16x32 frags/wave.
// R11 pipeline: 3-buffer LDS, depth-2 prefetch, counted vmcnt(4) + raw
// s_barrier per K-step (T4). Loads stay in flight across barriers; only
// the last iteration drains vmcnt(0).
// MODE 1: +bias, exact GELU, BLOCKED bf16 out (fc1 -> mid, K'=4096)
// MODE 2: gate_msa*val + resid_f32, row-major bf16 out (out-proj -> x2)
// MODE 3: +bias, gate_mlp*val + resid_bf16(row-major), f32 out (fc2 -> d_out)
// MODE 4: fused RoPE; q (aux1) row-major (b,h,s,d) scaled by
//         hd^-0.5*log2(e); k (aux2) attn-K-blocked; v (out_bf) attn-V-
//         blocked with PERMUTED rows (matches attn's paired P layout).
// ---------------------------------------------------------------------------
template<int MODE>
__global__ __launch_bounds__(256) void gemm128(
    const u16* __restrict__ A, const u16* __restrict__ W,
    int M, int N, int K,
    const float* __restrict__ mods, const float* __restrict__ bias,
    const float* __restrict__ resid_f, const u16* __restrict__ resid_bf,
    float* __restrict__ out_f, u16* __restrict__ out_bf,
    u16* __restrict__ aux1, u16* __restrict__ aux2,
    const float* __restrict__ rcos, const float* __restrict__ rsin)
{
    __shared__ u16 As[3][4096];
    __shared__ u16 Bs[3][4096];
    const int tid  = threadIdx.x;
    const int wave = tid >> 6, lane = tid & 63;
    const int quad = lane >> 4, l15 = lane & 15;
    const int wi = wave >> 1, wj = wave & 1;
    const int m0 = blockIdx.y * 128, n0 = blockIdx.x * 128;

    f32x4 acc[4][4] = {};

    const u16* Asrc = A + (size_t)m0 * K + wave * 1024 + lane * 8;
    const u16* Bsrc = W + (size_t)n0 * K + wave * 1024 + lane * 8;
    const int wo = wave * 1024;

    // stage tile tt into LDS buffer buf (4 loads per wave)
    auto stage = [&](int tt, int buf) {
        const u16* a = Asrc + (size_t)tt * 4096;
        const u16* b = Bsrc + (size_t)tt * 4096;
        dma16(a,       &As[buf][wo]);
        dma16(a + 512, &As[buf][wo + 512]);
        dma16(b,       &Bs[buf][wo]);
        dma16(b + 512, &Bs[buf][wo + 512]);
    };

    const int nt = K >> 5;           // >= 32 for all our shapes
    // prologue: tiles 0,1 into buffers 0,1 (8 loads in flight)
    stage(0, 0);
    stage(1, 1);

    int cur = 0;
    for (int t = 0; t < nt; ++t) {
        if (t + 1 < nt) {
            // own tile-t loads (all but the newest 4 = tile t+1's) complete
            __asm volatile("s_waitcnt vmcnt(4)" ::: "memory");
        } else {
            __asm volatile("s_waitcnt vmcnt(0)" ::: "memory");
        }
        __builtin_amdgcn_s_barrier();   // no compiler-forced vmcnt(0) drain
        if (t + 2 < nt) {
            int nb = cur + 2; if (nb >= 3) nb -= 3;
            stage(t + 2, nb);
        }
        bf16x8 af[4], bw[4];
        #pragma unroll
        for (int f = 0; f < 4; ++f) {
            af[f] = *(const bf16x8*)(&As[cur][quad * 1024 + (wi * 64 + f * 16 + l15) * 8]);
            bw[f] = *(const bf16x8*)(&Bs[cur][quad * 1024 + (wj * 64 + f * 16 + l15) * 8]);
        }
        #pragma unroll
        for (int fi = 0; fi < 4; ++fi)
            #pragma unroll
            for (int fj = 0; fj < 4; ++fj)
                acc[fi][fj] = MFMA_BF16(af[fi], bw[fj], acc[fi][fj]);
        cur = (cur + 1 == 3) ? 0 : cur + 1;
    }

    if (MODE == 4) {
        const int colbase = n0 + wj * 64;
        const int wcol = colbase >> 10;            // 0=q, 1=k, 2=v
        const int hh   = (colbase & 1023) >> 6;
        #pragma unroll
        for (int fi = 0; fi < 4; ++fi) {
            const int rbase = m0 + wi * 64 + fi * 16 + quad * 4;
            #pragma unroll
            for (int reg = 0; reg < 4; ++reg) {
                const int r = rbase + reg;
                const int b = r >> 11, s = r & 2047;
                const int bh = b * 16 + hh;
                #pragma unroll
                for (int fj = 0; fj < 2; ++fj) {
                    const int d2 = fj * 16 + l15;
                    float va = acc[fi][fj][reg];
                    float vb = acc[fi][fj + 2][reg];
                    float ca = rcos[s * 64 + d2];
                    float sa = rsin[s * 64 + d2];
                    float ra = va * ca - vb * sa;     // out[d]
                    float rb = vb * ca + va * sa;     // out[d+32]
                    if (wcol == 0) {
                        // hd^-0.5 * log2(e): softmax uses raw v_exp (2^x)
                        ra *= 0.18033688011f; rb *= 0.18033688011f;
                        u16* dst = aux1 + ((size_t)bh * 2048 + s) * 64;
                        dst[d2]      = f2b(ra);
                        dst[d2 + 32] = f2b(rb);
                    } else if (wcol == 1) {
                        size_t base = (size_t)bh * 131072 + (s >> 6) * 4096
                                    + (s & 63) * 8 + (d2 & 7);
                        aux2[base + (d2 >> 3) * 512]        = f2b(ra);
                        aux2[base + ((d2 >> 3) + 4) * 512]  = f2b(rb);
                    } else {
                        // permuted row: matches attn's paired P-store layout
                        const int sl = s & 63;
                        const int sp = (sl & 32) | ((sl & 15) << 1) | ((sl >> 4) & 1);
                        size_t base = (size_t)bh * 131072 + (s >> 6) * 4096
                                    + (sp >> 3) * 512 + (sp & 7);
                        out_bf[base + d2 * 8]        = f2b(ra);
                        out_bf[base + (d2 + 32) * 8] = f2b(rb);
                    }
                }
            }
        }
        return;
    }

    #pragma unroll
    for (int fi = 0; fi < 4; ++fi) {
        #pragma unroll
        for (int fj = 0; fj < 4; ++fj) {
            const int cidx  = n0 + wj * 64 + fj * 16 + l15;
            const int rbase = m0 + wi * 64 + fi * 16 + quad * 4;
            #pragma unroll
            for (int reg = 0; reg < 4; ++reg) {
                const int r = rbase + reg;
                float v = acc[fi][fj][reg];
                if (MODE == 1) {
                    float u = v + bias[cidx];
                    float g = 0.5f * u * (1.0f + erff(u * 0.70710678118654752f));
                    size_t o = ((size_t)(r >> 7)) * 524288 + (cidx >> 3) * 1024
                             + (r & 127) * 8 + (cidx & 7);
                    out_bf[o] = f2b(g);
                } else if (MODE == 2) {
                    int bb = r >> 11;
                    float gate = mods[bb * 6144 + 2048 + cidx];  // gate_msa
                    out_bf[(size_t)r * N + cidx] = f2b(gate * v + resid_f[(size_t)r * N + cidx]);
                } else if (MODE == 3) {
                    int bb = r >> 11;
                    float u = v + bias[cidx];
                    float gate = mods[bb * 6144 + 5120 + cidx];  // gate_mlp
                    out_f[(size_t)r * N + cidx] =
                        finz(gate * u + b2f(resid_bf[(size_t)r * N + cidx]));
                }
            }
        }
    }
}

// ---------------------------------------------------------------------------
// Flash attention, R14: R8 structure (single-buffer KV, 25.6KB LDS,
// 4 blocks/CU) + VALU cuts: raw v_exp_f32 softmax (Q pre-scaled by log2 e;
// clamp 72 in log2 space = e^49.9 equivalent), paired u32 P-stores into the
// k-permuted layout matched by V's blocked rows (PV invariant under shared
// contraction permutation). Deferred denominator.
// Block = (b,h, 64-query tile): 1024 blocks. 4 waves x 16 q.
// ---------------------------------------------------------------------------
__global__ __launch_bounds__(256) void attn_kernel(
    const u16* __restrict__ Q, const u16* __restrict__ Kb,
    const u16* __restrict__ Vb, u16* __restrict__ O)
{
    __shared__ u16 Ks[4096];
    __shared__ u16 Vs[4096];
    __shared__ u16 Ps[4][16 * 72];
    const int tid  = threadIdx.x;
    const int wave = tid >> 6, lane = tid & 63;
    const int quad = lane >> 4, l15 = lane & 15;
    const int bh = blockIdx.x & 31, qt = blockIdx.x >> 5;

    const u16* Qh = Q  + ((size_t)bh * 2048 + qt * 64) * 64;
    const u16* Kh = Kb + (size_t)bh * 131072;
    const u16* Vh = Vb + (size_t)bh * 131072;

    bf16x8 aq[2];
    #pragma unroll
    for (int kh = 0; kh < 2; ++kh)
        aq[kh] = *(const bf16x8*)(Qh + (size_t)(wave * 16 + l15) * 64 + kh * 32 + quad * 8);

    f32x4 acc_o[4] = {};
    float lsum[4] = {0.f, 0.f, 0.f, 0.f};

    for (int kb = 0; kb < 32; ++kb) {
        __syncthreads();
        const u16* kc = Kh + kb * 4096;
        const u16* vc = Vh + kb * 4096;
        dma16(kc + (2 * wave) * 512 + lane * 8,     &Ks[(2 * wave) * 512]);
        dma16(kc + (2 * wave + 1) * 512 + lane * 8, &Ks[(2 * wave + 1) * 512]);
        dma16(vc + (2 * wave) * 512 + lane * 8,     &Vs[(2 * wave) * 512]);
        dma16(vc + (2 * wave + 1) * 512 + lane * 8, &Vs[(2 * wave + 1) * 512]);
        __syncthreads();

        f32x4 sc[4] = {};
        #pragma unroll
        for (int kt = 0; kt < 4; ++kt)
            #pragma unroll
            for (int kh = 0; kh < 2; ++kh) {
                bf16x8 bk = *(const bf16x8*)(&Ks[(quad + kh * 4) * 512 + (kt * 16 + l15) * 8]);
                sc[kt] = MFMA_BF16(aq[kh], bk, sc[kt]);
            }

        // p = 2^s (Q carries log2 e); clamp is overflow/NaN safety only.
        #pragma unroll
        for (int kt = 0; kt < 4; ++kt)
            #pragma unroll
            for (int reg = 0; reg < 4; ++reg)
                sc[kt][reg] = exp2_raw(fminf(sc[kt][reg], 72.f));
        #pragma unroll
        for (int reg = 0; reg < 4; ++reg)
            lsum[reg] += (sc[0][reg] + sc[1][reg]) + (sc[2][reg] + sc[3][reg]);

        // P: C-layout -> A-layout via wave-private LDS, paired u32 stores.
        // u16 col c holds k = 16*(c&1) + (c>>1) per 32-block; V rows are
        // permuted identically at write time (MODE 4), so PV is exact.
        #pragma unroll
        for (int reg = 0; reg < 4; ++reg) {
            u32* prow = (u32*)(&Ps[wave][(quad * 4 + reg) * 72]);
            prow[l15]      = pk2(sc[0][reg], sc[1][reg]);
            prow[16 + l15] = pk2(sc[2][reg], sc[3][reg]);
        }
        __asm volatile("s_waitcnt lgkmcnt(0)" ::: "memory");

        bf16x8 ap0 = *(const bf16x8*)(&Ps[wave][l15 * 72 + quad * 8]);
        bf16x8 ap1 = *(const bf16x8*)(&Ps[wave][l15 * 72 + 32 + quad * 8]);
        #pragma unroll
        for (int dt = 0; dt < 4; ++dt) {
            bf16x8 bv0 = *(const bf16x8*)(&Vs[quad * 512 + (dt * 16 + l15) * 8]);
            bf16x8 bv1 = *(const bf16x8*)(&Vs[(quad + 4) * 512 + (dt * 16 + l15) * 8]);
            acc_o[dt] = MFMA_BF16(ap0, bv0, acc_o[dt]);
            acc_o[dt] = MFMA_BF16(ap1, bv1, acc_o[dt]);
        }
    }

    // deferred denominator: reduce partial sums across the 16 lanes of the quad
    float linv[4];
    #pragma unroll
    for (int reg = 0; reg < 4; ++reg) {
        float l = lsum[reg];
        l += __shfl_xor(l, 1, 64);
        l += __shfl_xor(l, 2, 64);
        l += __shfl_xor(l, 4, 64);
        l += __shfl_xor(l, 8, 64);
        linv[reg] = 1.0f / l;
    }

    // O write in GEMM-blocked layout (out-proj A-operand, K=1024)
    const int b = bh >> 4, hh = bh & 15;
    #pragma unroll
    for (int dt = 0; dt < 4; ++dt)
        #pragma unroll
        for (int reg = 0; reg < 4; ++reg) {
            int q = qt * 64 + wave * 16 + quad * 4 + reg;
            int r = b * 2048 + q;
            int col = hh * 64 + dt * 16 + l15;
            float v = acc_o[dt][reg] * linv[reg];
            O[((size_t)(r >> 7)) * 131072 + (col >> 3) * 1024
              + (r & 127) * 8 + (col & 7)] = f2b(v);
        }
}

// ---------------------------------------------------------------------------
extern "C" void kernel_launch(void* const* d_in, const int* in_sizes, int n_in,
                              void* d_out, int out_size, void* d_ws, size_t ws_size,
                              hipStream_t stream)
{
    const float* x     = (const float*)d_in[0];
    const float* rcos  = (const float*)d_in[1];
    const float* rsin  = (const float*)d_in[2];
    const float* c     = (const float*)d_in[3];
    const float* n1w   = (const float*)d_in[4];
    const float* qkvw  = (const float*)d_in[5];
    const float* outw  = (const float*)d_in[6];
    const float* n2w   = (const float*)d_in[7];
    const float* fc1w  = (const float*)d_in[8];
    const float* fc1b  = (const float*)d_in[9];
    const float* fc2w  = (const float*)d_in[10];
    const float* fc2b  = (const float*)d_in[11];
    const float* adaw  = (const float*)d_in[12];
    const float* adab  = (const float*)d_in[13];
    float* out = (float*)d_out;

    // Arena (48 MB + 48 KB): [mods 48K][W 8M][S1 8M][S2 8M][S3 8M][S4 16M]
    char* ws = (char*)d_ws;
    const size_t MB8 = (size_t)8 * 1024 * 1024;
    float* mods  = (float*)ws;
    u16*   W     = (u16*)(ws + 49152);
    char*  S1    = ws + 49152 + MB8;
    char*  S2    = S1 + MB8;

    u16* h    = (u16*)d_out;       // LN1 out, blocked
    u16* qs   = (u16*)S1;          // (b,h,s,d) row-major, pre-scaled
    u16* ks   = (u16*)S2;          // attn-K blocked
    u16* vT   = (u16*)(S2 + MB8);  // attn-V blocked (permuted rows)
    u16* ob   = (u16*)d_out;       // attn out, GEMM-blocked
    u16* x2   = (u16*)S1;          // bf16 residual, row-major
    u16* h2   = (u16*)d_out;       // LN2 out, blocked
    u16* mid  = (u16*)S2;          // 32 MB, blocked (K'=4096)

    mods_kernel<<<6144, 64, 0, stream>>>(c, adaw, adab, mods);
    ln_mod_kernel<<<4096, 256, 0, stream>>>(nullptr, x, n1w, mods, 1024, 0, h);
    // qkv (+fused RoPE scatter)
    convert_kernel<<<1536, 256, 0, stream>>>(qkvw, W, 393216, 10);
    gemm128<4><<<dim3(24, 32), 256, 0, stream>>>(h, W, 4096, 3072, 1024,
        nullptr, nullptr, nullptr, nullptr, nullptr, vT, qs, ks, rcos, rsin);
    attn_kernel<<<1024, 256, 0, stream>>>(qs, ks, vT, ob);
    // x2 = gate_msa * (o @ out_w^T) + x
    convert_kernel<<<512, 256, 0, stream>>>(outw, W, 131072, 10);
    gemm128<2><<<dim3(8, 32), 256, 0, stream>>>(ob, W, 4096, 1024, 1024,
        mods, nullptr, x, nullptr, nullptr, x2, nullptr, nullptr, nullptr, nullptr);
    // h2 = LN(x2)*(1+scale_mlp)+shift_mlp
    ln_mod_kernel<<<4096, 256, 0, stream>>>(x2, nullptr, n2w, mods, 4096, 3072, h2);
    // mid = gelu(h2 @ fc1_w^T + fc1_b)
    convert_kernel<<<2048, 256, 0, stream>>>(fc1w, W, 524288, 10);
    gemm128<1><<<dim3(32, 32), 256, 0, stream>>>(h2, W, 4096, 4096, 1024,
        nullptr, fc1b, nullptr, nullptr, nullptr, mid, nullptr, nullptr, nullptr, nullptr);
    // out = gate_mlp * (mid @ fc2_w^T + fc2_b) + x2
    convert_kernel<<<2048, 256, 0, stream>>>(fc2w, W, 524288, 12);
    gemm128<3><<<dim3(8, 32), 256, 0, stream>>>(mid, W, 4096, 1024, 4096,
        mods, fc2b, nullptr, x2, out, nullptr, nullptr, nullptr, nullptr, nullptr);
}

// Round 8
// 410.182 us; speedup vs baseline: 1.0368x; 1.0368x over previous
//
#include <hip/hip_runtime.h>
#include <hip/hip_bf16.h>

// TransformerBlock: B=2, S=2048, D=1024, H=16, hd=64, C=1024
// External tensors f32; internal bf16 MFMA (f32 accum).
// R15: attn register-pressure fix. R14 counters: VALUBusy 54% = ~364 VALU
// inst/wave/iter vs ~60 static — at VGPR_Count=40 the allocator remat's
// loop-invariant addresses every iteration. Occupancy is grid-capped at
// 4 blocks/CU (1024 blocks), so VGPR<=128 is free: __launch_bounds__(256,4)
// raises the budget; staging uses hoisted pointer-bump bases. Softmax/
// P-transpose/PV body identical to R14 (raw v_exp, paired u32 P-stores with
// k-permutation matched by V's blocked rows).
// Pipeline lessons held: GEMMs (low-occupancy) use counted-vmcnt pipeline
// (R11); attn (4 blocks/CU) stays single-buffered (R9/R12/R13 all lost).
// Workspace: 48 MB + 48 KB.
//
// Blocked layout (bf16, inner-dim K): for row r, col k:
//   idx = (r>>7)*128*K + (k>>3)*1024 + (r&127)*8 + (k&7)
// attn K per (b,h): idx = kb*4096 + (d>>3)*512 + (s&63)*8 + (d&7), kb=s>>6
// attn V per (b,h): PERMUTED rows sp = (s&32)|((s&15)<<1)|((s>>4)&1):
//   idx = kb*4096 + (sp>>3)*512 + d*8 + (sp&7)

typedef unsigned short u16;
typedef unsigned int   u32;
typedef __bf16 bf16x8 __attribute__((ext_vector_type(8)));
typedef float  f32x4  __attribute__((ext_vector_type(4)));

#define MFMA_BF16(a, b, c) __builtin_amdgcn_mfma_f32_16x16x32_bf16((a), (b), (c), 0, 0, 0)

__device__ __forceinline__ float b2f(u16 u) {
    union { u32 i; float f; } v; v.i = ((u32)u) << 16; return v.f;
}
__device__ __forceinline__ u16 f2b(float f) {
    union { u32 i; float f; } v; v.f = f;
    u32 i = v.i;
    return (u16)((i + 0x7FFFu + ((i >> 16) & 1u)) >> 16);  // RNE
}
// packed f32x2 -> bf16x2 (low = a, high = b)
__device__ __forceinline__ u32 pk2(float a, float b) {
#if __has_builtin(__builtin_amdgcn_cvt_pk_bf16_f32)
    typedef __bf16 bf16x2_t __attribute__((ext_vector_type(2)));
    union { bf16x2_t v; u32 u; } cv;
    cv.v = __builtin_amdgcn_cvt_pk_bf16_f32(a, b);
    return cv.u;
#else
    return (u32)f2b(a) | ((u32)f2b(b) << 16);
#endif
}
// raw v_exp_f32 (2^x), no libcall wrapper
__device__ __forceinline__ float exp2_raw(float x) {
#if __has_builtin(__builtin_amdgcn_exp2f)
    return __builtin_amdgcn_exp2f(x);
#else
    float r;
    __asm("v_exp_f32 %0, %1" : "=v"(r) : "v"(x));
    return r;
#endif
}
__device__ __forceinline__ float finz(float v) {
    return __builtin_isfinite(v) ? v : 0.0f;
}
__device__ __forceinline__ void dma16(const void* g, void* l) {
    __builtin_amdgcn_global_load_lds(
        (const __attribute__((address_space(1))) unsigned int*)(uintptr_t)g,
        (__attribute__((address_space(3))) unsigned int*)(uintptr_t)l,
        16, 0, 0);
}

// ---------------------------------------------------------------------------
// f32 -> bf16 blocked weight conversion. Thread i emits 8 contiguous u16 of
// the blocked output (one (row, kg) cell); reads 8 contiguous floats.
// ---------------------------------------------------------------------------
__global__ __launch_bounds__(256) void convert_kernel(
    const float* __restrict__ in, u16* __restrict__ out, int n8, int kshift)
{
    int i = blockIdx.x * 256 + threadIdx.x;
    if (i >= n8) return;
    size_t o = (size_t)i * 8;
    int bk   = (int)(o >> (kshift + 7));
    int rem  = (int)(o & (((size_t)128 << kshift) - 1));
    int kg   = rem >> 10;
    int nloc = (rem >> 3) & 127;
    const float* src = in + (((size_t)bk * 128 + nloc) << kshift) + kg * 8;
    float4 a = *(const float4*)src;
    float4 b = *(const float4*)(src + 4);
    union { u16 s[8]; float4 v; } wp;
    wp.s[0] = f2b(a.x); wp.s[1] = f2b(a.y); wp.s[2] = f2b(a.z); wp.s[3] = f2b(a.w);
    wp.s[4] = f2b(b.x); wp.s[5] = f2b(b.y); wp.s[6] = f2b(b.z); wp.s[7] = f2b(b.w);
    *(float4*)(out + o) = wp.v;
}

// ---------------------------------------------------------------------------
// mods = c @ ada_w.T + ada_b : (2, 6144), K=1024, f32. One wave per column.
// ---------------------------------------------------------------------------
__global__ __launch_bounds__(64) void mods_kernel(
    const float* __restrict__ c, const float* __restrict__ ada_w,
    const float* __restrict__ ada_b, float* __restrict__ mods)
{
    const int n = blockIdx.x;
    const int lane = threadIdx.x;
    const float* wr = ada_w + (size_t)n * 1024;
    float a0 = 0.f, a1 = 0.f;
    for (int k = lane; k < 1024; k += 64) {
        float w = wr[k];
        a0 += w * c[k];
        a1 += w * c[1024 + k];
    }
    for (int o = 32; o > 0; o >>= 1) {
        a0 += __shfl_down(a0, o, 64);
        a1 += __shfl_down(a1, o, 64);
    }
    if (lane == 0) {
        float bb = ada_b[n];
        mods[n]        = a0 + bb;
        mods[6144 + n] = a1 + bb;
    }
}

// ---------------------------------------------------------------------------
// LayerNorm + adaLN modulation. Input f32 (xf) or bf16 row-major (xbf).
// Output bf16 in BLOCKED layout (K=1024).
// ---------------------------------------------------------------------------
__global__ __launch_bounds__(256) void ln_mod_kernel(
    const u16* __restrict__ xbf, const float* __restrict__ xf,
    const float* __restrict__ w, const float* __restrict__ mods,
    int scale_off, int shift_off, u16* __restrict__ out)
{
    const int row = blockIdx.x;          // b*2048 + s
    const int b   = row >> 11;
    const int tid = threadIdx.x;
    const size_t base = (size_t)row * 1024 + tid * 4;
    float v[4];
    if (xf) {
        float4 t = *(const float4*)(xf + base);
        v[0] = t.x; v[1] = t.y; v[2] = t.z; v[3] = t.w;
    } else {
        uint2 p = *(const uint2*)(xbf + base);
        union { u32 i; float f; } a, bb, cc, d;
        a.i  = p.x << 16;          v[0] = a.f;
        bb.i = p.x & 0xFFFF0000u;  v[1] = bb.f;
        cc.i = p.y << 16;          v[2] = cc.f;
        d.i  = p.y & 0xFFFF0000u;  v[3] = d.f;
    }
    float s  = v[0] + v[1] + v[2] + v[3];
    float sq = v[0]*v[0] + v[1]*v[1] + v[2]*v[2] + v[3]*v[3];
    __shared__ float rs[256], rq[256];
    rs[tid] = s; rq[tid] = sq;
    __syncthreads();
    for (int o = 128; o > 0; o >>= 1) {
        if (tid < o) { rs[tid] += rs[tid + o]; rq[tid] += rq[tid + o]; }
        __syncthreads();
    }
    const float mean = rs[0] * (1.0f / 1024.0f);
    const float var  = rq[0] * (1.0f / 1024.0f) - mean * mean;
    const float inv  = rsqrtf(fmaxf(var, 0.f) + 1e-5f);
    union { u16 s4[4]; uint2 u2; } pk;
    for (int i = 0; i < 4; ++i) {
        int cidx = tid * 4 + i;
        float y = (v[i] - mean) * inv * w[cidx];
        y = y * (1.0f + mods[b * 6144 + scale_off + cidx]) + mods[b * 6144 + shift_off + cidx];
        pk.s4[i] = f2b(y);
    }
    size_t o = ((size_t)(row >> 7)) * 131072 + ((tid * 4) >> 3) * 1024
             + (row & 127) * 8 + ((tid * 4) & 7);
    *(uint2*)(out + o) = pk.u2;
}

// ---------------------------------------------------------------------------
// m97-style GEMM on BLOCKED operands: C[M,N] = A[M,K] @ W[N,K]^T.
// 128x128 tile, BK=32, 4 waves (2x2), 4x4 16x16x32 frags/wave.
// R11 pipeline: 3-buffer LDS, depth-2 prefetch, counted vmcnt(4) + raw
// s_barrier per K-step (T4). Loads stay in flight across barriers; only
// the last iteration drains vmcnt(0).
// MODE 1: +bias, exact GELU, BLOCKED bf16 out (fc1 -> mid, K'=4096)
// MODE 2: gate_msa*val + resid_f32, row-major bf16 out (out-proj -> x2)
// MODE 3: +bias, gate_mlp*val + resid_bf16(row-major), f32 out (fc2 -> d_out)
// MODE 4: fused RoPE; q (aux1) row-major (b,h,s,d) scaled by
//         hd^-0.5*log2(e); k (aux2) attn-K-blocked; v (out_bf) attn-V-
//         blocked with PERMUTED rows (matches attn's paired P layout).
// ---------------------------------------------------------------------------
template<int MODE>
__global__ __launch_bounds__(256) void gemm128(
    const u16* __restrict__ A, const u16* __restrict__ W,
    int M, int N, int K,
    const float* __restrict__ mods, const float* __restrict__ bias,
    const float* __restrict__ resid_f, const u16* __restrict__ resid_bf,
    float* __restrict__ out_f, u16* __restrict__ out_bf,
    u16* __restrict__ aux1, u16* __restrict__ aux2,
    const float* __restrict__ rcos, const float* __restrict__ rsin)
{
    __shared__ u16 As[3][4096];
    __shared__ u16 Bs[3][4096];
    const int tid  = threadIdx.x;
    const int wave = tid >> 6, lane = tid & 63;
    const int quad = lane >> 4, l15 = lane & 15;
    const int wi = wave >> 1, wj = wave & 1;
    const int m0 = blockIdx.y * 128, n0 = blockIdx.x * 128;

    f32x4 acc[4][4] = {};

    const u16* Asrc = A + (size_t)m0 * K + wave * 1024 + lane * 8;
    const u16* Bsrc = W + (size_t)n0 * K + wave * 1024 + lane * 8;
    const int wo = wave * 1024;

    // stage tile tt into LDS buffer buf (4 loads per wave)
    auto stage = [&](int tt, int buf) {
        const u16* a = Asrc + (size_t)tt * 4096;
        const u16* b = Bsrc + (size_t)tt * 4096;
        dma16(a,       &As[buf][wo]);
        dma16(a + 512, &As[buf][wo + 512]);
        dma16(b,       &Bs[buf][wo]);
        dma16(b + 512, &Bs[buf][wo + 512]);
    };

    const int nt = K >> 5;           // >= 32 for all our shapes
    // prologue: tiles 0,1 into buffers 0,1 (8 loads in flight)
    stage(0, 0);
    stage(1, 1);

    int cur = 0;
    for (int t = 0; t < nt; ++t) {
        if (t + 1 < nt) {
            // own tile-t loads (all but the newest 4 = tile t+1's) complete
            __asm volatile("s_waitcnt vmcnt(4)" ::: "memory");
        } else {
            __asm volatile("s_waitcnt vmcnt(0)" ::: "memory");
        }
        __builtin_amdgcn_s_barrier();   // no compiler-forced vmcnt(0) drain
        if (t + 2 < nt) {
            int nb = cur + 2; if (nb >= 3) nb -= 3;
            stage(t + 2, nb);
        }
        bf16x8 af[4], bw[4];
        #pragma unroll
        for (int f = 0; f < 4; ++f) {
            af[f] = *(const bf16x8*)(&As[cur][quad * 1024 + (wi * 64 + f * 16 + l15) * 8]);
            bw[f] = *(const bf16x8*)(&Bs[cur][quad * 1024 + (wj * 64 + f * 16 + l15) * 8]);
        }
        #pragma unroll
        for (int fi = 0; fi < 4; ++fi)
            #pragma unroll
            for (int fj = 0; fj < 4; ++fj)
                acc[fi][fj] = MFMA_BF16(af[fi], bw[fj], acc[fi][fj]);
        cur = (cur + 1 == 3) ? 0 : cur + 1;
    }

    if (MODE == 4) {
        const int colbase = n0 + wj * 64;
        const int wcol = colbase >> 10;            // 0=q, 1=k, 2=v
        const int hh   = (colbase & 1023) >> 6;
        #pragma unroll
        for (int fi = 0; fi < 4; ++fi) {
            const int rbase = m0 + wi * 64 + fi * 16 + quad * 4;
            #pragma unroll
            for (int reg = 0; reg < 4; ++reg) {
                const int r = rbase + reg;
                const int b = r >> 11, s = r & 2047;
                const int bh = b * 16 + hh;
                #pragma unroll
                for (int fj = 0; fj < 2; ++fj) {
                    const int d2 = fj * 16 + l15;
                    float va = acc[fi][fj][reg];
                    float vb = acc[fi][fj + 2][reg];
                    float ca = rcos[s * 64 + d2];
                    float sa = rsin[s * 64 + d2];
                    float ra = va * ca - vb * sa;     // out[d]
                    float rb = vb * ca + va * sa;     // out[d+32]
                    if (wcol == 0) {
                        // hd^-0.5 * log2(e): softmax uses raw v_exp (2^x)
                        ra *= 0.18033688011f; rb *= 0.18033688011f;
                        u16* dst = aux1 + ((size_t)bh * 2048 + s) * 64;
                        dst[d2]      = f2b(ra);
                        dst[d2 + 32] = f2b(rb);
                    } else if (wcol == 1) {
                        size_t base = (size_t)bh * 131072 + (s >> 6) * 4096
                                    + (s & 63) * 8 + (d2 & 7);
                        aux2[base + (d2 >> 3) * 512]        = f2b(ra);
                        aux2[base + ((d2 >> 3) + 4) * 512]  = f2b(rb);
                    } else {
                        // permuted row: matches attn's paired P-store layout
                        const int sl = s & 63;
                        const int sp = (sl & 32) | ((sl & 15) << 1) | ((sl >> 4) & 1);
                        size_t base = (size_t)bh * 131072 + (s >> 6) * 4096
                                    + (sp >> 3) * 512 + (sp & 7);
                        out_bf[base + d2 * 8]        = f2b(ra);
                        out_bf[base + (d2 + 32) * 8] = f2b(rb);
                    }
                }
            }
        }
        return;
    }

    #pragma unroll
    for (int fi = 0; fi < 4; ++fi) {
        #pragma unroll
        for (int fj = 0; fj < 4; ++fj) {
            const int cidx  = n0 + wj * 64 + fj * 16 + l15;
            const int rbase = m0 + wi * 64 + fi * 16 + quad * 4;
            #pragma unroll
            for (int reg = 0; reg < 4; ++reg) {
                const int r = rbase + reg;
                float v = acc[fi][fj][reg];
                if (MODE == 1) {
                    float u = v + bias[cidx];
                    float g = 0.5f * u * (1.0f + erff(u * 0.70710678118654752f));
                    size_t o = ((size_t)(r >> 7)) * 524288 + (cidx >> 3) * 1024
                             + (r & 127) * 8 + (cidx & 7);
                    out_bf[o] = f2b(g);
                } else if (MODE == 2) {
                    int bb = r >> 11;
                    float gate = mods[bb * 6144 + 2048 + cidx];  // gate_msa
                    out_bf[(size_t)r * N + cidx] = f2b(gate * v + resid_f[(size_t)r * N + cidx]);
                } else if (MODE == 3) {
                    int bb = r >> 11;
                    float u = v + bias[cidx];
                    float gate = mods[bb * 6144 + 5120 + cidx];  // gate_mlp
                    out_f[(size_t)r * N + cidx] =
                        finz(gate * u + b2f(resid_bf[(size_t)r * N + cidx]));
                }
            }
        }
    }
}

// ---------------------------------------------------------------------------
// Flash attention, R15: R14 body + register-pressure fix.
// __launch_bounds__(256, 4): grid caps occupancy at 4 blocks/CU (= 4 waves/
// SIMD), so VGPR<=128 is free — stop the allocator's 40-VGPR remat storm.
// Staging addresses are hoisted pointer-bumps (one += per iter, no per-iter
// 64-bit address math). Raw v_exp softmax (Q pre-scaled by log2 e), paired
// u32 P-stores (k-permutation matched by V rows), deferred denominator.
// Block = (b,h, 64-query tile): 1024 blocks. 4 waves x 16 q.
// ---------------------------------------------------------------------------
__global__ __launch_bounds__(256, 4) void attn_kernel(
    const u16* __restrict__ Q, const u16* __restrict__ Kb,
    const u16* __restrict__ Vb, u16* __restrict__ O)
{
    __shared__ u16 Ks[4096];
    __shared__ u16 Vs[4096];
    __shared__ u16 Ps[4][16 * 72];
    const int tid  = threadIdx.x;
    const int wave = tid >> 6, lane = tid & 63;
    const int quad = lane >> 4, l15 = lane & 15;
    const int bh = blockIdx.x & 31, qt = blockIdx.x >> 5;

    const u16* Qh = Q + ((size_t)bh * 2048 + qt * 64) * 64;

    // hoisted staging bases: one pointer-bump per iteration, LDS dsts const
    const int soff = (2 * wave) * 512 + lane * 8;
    const u16* kSrc = Kb + (size_t)bh * 131072 + soff;
    const u16* vSrc = Vb + (size_t)bh * 131072 + soff;
    u16* kDst0 = &Ks[(2 * wave) * 512];
    u16* kDst1 = &Ks[(2 * wave + 1) * 512];
    u16* vDst0 = &Vs[(2 * wave) * 512];
    u16* vDst1 = &Vs[(2 * wave + 1) * 512];

    bf16x8 aq[2];
    #pragma unroll
    for (int kh = 0; kh < 2; ++kh)
        aq[kh] = *(const bf16x8*)(Qh + (size_t)(wave * 16 + l15) * 64 + kh * 32 + quad * 8);

    f32x4 acc_o[4] = {};
    float lsum[4] = {0.f, 0.f, 0.f, 0.f};

    for (int kb = 0; kb < 32; ++kb) {
        __syncthreads();
        dma16(kSrc,       kDst0);
        dma16(kSrc + 512, kDst1);
        dma16(vSrc,       vDst0);
        dma16(vSrc + 512, vDst1);
        kSrc += 4096; vSrc += 4096;
        __syncthreads();

        f32x4 sc[4] = {};
        #pragma unroll
        for (int kt = 0; kt < 4; ++kt)
            #pragma unroll
            for (int kh = 0; kh < 2; ++kh) {
                bf16x8 bk = *(const bf16x8*)(&Ks[(quad + kh * 4) * 512 + (kt * 16 + l15) * 8]);
                sc[kt] = MFMA_BF16(aq[kh], bk, sc[kt]);
            }

        // p = 2^s (Q carries log2 e); clamp is overflow/NaN safety only.
        #pragma unroll
        for (int kt = 0; kt < 4; ++kt)
            #pragma unroll
            for (int reg = 0; reg < 4; ++reg)
                sc[kt][reg] = exp2_raw(fminf(sc[kt][reg], 72.f));
        #pragma unroll
        for (int reg = 0; reg < 4; ++reg)
            lsum[reg] += (sc[0][reg] + sc[1][reg]) + (sc[2][reg] + sc[3][reg]);

        // P: C-layout -> A-layout via wave-private LDS, paired u32 stores.
        // u16 col c holds k = 16*(c&1) + (c>>1) per 32-block; V rows are
        // permuted identically at write time (MODE 4), so PV is exact.
        #pragma unroll
        for (int reg = 0; reg < 4; ++reg) {
            u32* prow = (u32*)(&Ps[wave][(quad * 4 + reg) * 72]);
            prow[l15]      = pk2(sc[0][reg], sc[1][reg]);
            prow[16 + l15] = pk2(sc[2][reg], sc[3][reg]);
        }
        __asm volatile("s_waitcnt lgkmcnt(0)" ::: "memory");

        bf16x8 ap0 = *(const bf16x8*)(&Ps[wave][l15 * 72 + quad * 8]);
        bf16x8 ap1 = *(const bf16x8*)(&Ps[wave][l15 * 72 + 32 + quad * 8]);
        #pragma unroll
        for (int dt = 0; dt < 4; ++dt) {
            bf16x8 bv0 = *(const bf16x8*)(&Vs[quad * 512 + (dt * 16 + l15) * 8]);
            bf16x8 bv1 = *(const bf16x8*)(&Vs[(quad + 4) * 512 + (dt * 16 + l15) * 8]);
            acc_o[dt] = MFMA_BF16(ap0, bv0, acc_o[dt]);
            acc_o[dt] = MFMA_BF16(ap1, bv1, acc_o[dt]);
        }
    }

    // deferred denominator: reduce partial sums across the 16 lanes of the quad
    float linv[4];
    #pragma unroll
    for (int reg = 0; reg < 4; ++reg) {
        float l = lsum[reg];
        l += __shfl_xor(l, 1, 64);
        l += __shfl_xor(l, 2, 64);
        l += __shfl_xor(l, 4, 64);
        l += __shfl_xor(l, 8, 64);
        linv[reg] = 1.0f / l;
    }

    // O write in GEMM-blocked layout (out-proj A-operand, K=1024)
    const int b = bh >> 4, hh = bh & 15;
    #pragma unroll
    for (int dt = 0; dt < 4; ++dt)
        #pragma unroll
        for (int reg = 0; reg < 4; ++reg) {
            int q = qt * 64 + wave * 16 + quad * 4 + reg;
            int r = b * 2048 + q;
            int col = hh * 64 + dt * 16 + l15;
            float v = acc_o[dt][reg] * linv[reg];
            O[((size_t)(r >> 7)) * 131072 + (col >> 3) * 1024
              + (r & 127) * 8 + (col & 7)] = f2b(v);
        }
}

// ---------------------------------------------------------------------------
extern "C" void kernel_launch(void* const* d_in, const int* in_sizes, int n_in,
                              void* d_out, int out_size, void* d_ws, size_t ws_size,
                              hipStream_t stream)
{
    const float* x     = (const float*)d_in[0];
    const float* rcos  = (const float*)d_in[1];
    const float* rsin  = (const float*)d_in[2];
    const float* c     = (const float*)d_in[3];
    const float* n1w   = (const float*)d_in[4];
    const float* qkvw  = (const float*)d_in[5];
    const float* outw  = (const float*)d_in[6];
    const float* n2w   = (const float*)d_in[7];
    const float* fc1w  = (const float*)d_in[8];
    const float* fc1b  = (const float*)d_in[9];
    const float* fc2w  = (const float*)d_in[10];
    const float* fc2b  = (const float*)d_in[11];
    const float* adaw  = (const float*)d_in[12];
    const float* adab  = (const float*)d_in[13];
    float* out = (float*)d_out;

    // Arena (48 MB + 48 KB): [mods 48K][W 8M][S1 8M][S2 8M][S3 8M][S4 16M]
    char* ws = (char*)d_ws;
    const size_t MB8 = (size_t)8 * 1024 * 1024;
    float* mods  = (float*)ws;
    u16*   W     = (u16*)(ws + 49152);
    char*  S1    = ws + 49152 + MB8;
    char*  S2    = S1 + MB8;

    u16* h    = (u16*)d_out;       // LN1 out, blocked
    u16* qs   = (u16*)S1;          // (b,h,s,d) row-major, pre-scaled
    u16* ks   = (u16*)S2;          // attn-K blocked
    u16* vT   = (u16*)(S2 + MB8);  // attn-V blocked (permuted rows)
    u16* ob   = (u16*)d_out;       // attn out, GEMM-blocked
    u16* x2   = (u16*)S1;          // bf16 residual, row-major
    u16* h2   = (u16*)d_out;       // LN2 out, blocked
    u16* mid  = (u16*)S2;          // 32 MB, blocked (K'=4096)

    mods_kernel<<<6144, 64, 0, stream>>>(c, adaw, adab, mods);
    ln_mod_kernel<<<4096, 256, 0, stream>>>(nullptr, x, n1w, mods, 1024, 0, h);
    // qkv (+fused RoPE scatter)
    convert_kernel<<<1536, 256, 0, stream>>>(qkvw, W, 393216, 10);
    gemm128<4><<<dim3(24, 32), 256, 0, stream>>>(h, W, 4096, 3072, 1024,
        nullptr, nullptr, nullptr, nullptr, nullptr, vT, qs, ks, rcos, rsin);
    attn_kernel<<<1024, 256, 0, stream>>>(qs, ks, vT, ob);
    // x2 = gate_msa * (o @ out_w^T) + x
    convert_kernel<<<512, 256, 0, stream>>>(outw, W, 131072, 10);
    gemm128<2><<<dim3(8, 32), 256, 0, stream>>>(ob, W, 4096, 1024, 1024,
        mods, nullptr, x, nullptr, nullptr, x2, nullptr, nullptr, nullptr, nullptr);
    // h2 = LN(x2)*(1+scale_mlp)+shift_mlp
    ln_mod_kernel<<<4096, 256, 0, stream>>>(x2, nullptr, n2w, mods, 4096, 3072, h2);
    // mid = gelu(h2 @ fc1_w^T + fc1_b)
    convert_kernel<<<2048, 256, 0, stream>>>(fc1w, W, 524288, 10);
    gemm128<1><<<dim3(32, 32), 256, 0, stream>>>(h2, W, 4096, 4096, 1024,
        nullptr, fc1b, nullptr, nullptr, nullptr, mid, nullptr, nullptr, nullptr, nullptr);
    // out = gate_mlp * (mid @ fc2_w^T + fc2_b) + x2
    convert_kernel<<<2048, 256, 0, stream>>>(fc2w, W, 524288, 12);
    gemm128<3><<<dim3(8, 32), 256, 0, stream>>>(mid, W, 4096, 1024, 4096,
        mods, fc2b, nullptr, x2, out, nullptr, nullptr, nullptr, nullptr, nullptr);
}

// Round 9
// 383.959 us; speedup vs baseline: 1.1077x; 1.0683x over previous
//
#include <hip/hip_runtime.h>
#include <hip/hip_bf16.h>

// TransformerBlock: B=2, S=2048, D=1024, H=16, hd=64, C=1024
// External tensors f32; internal bf16 MFMA (f32 accum).
// R16: pipeline-wide cleanup (attn unchanged from R15's 69.0us).
//  (1) N=1024 GEMMs (fc2, out-proj) re-tiled 64x128 -> grid 512 = 2
//      blocks/CU (were 256 = 1/CU, zero TLP margin). Waves 2x2 cover
//      32rowsx64cols each; per-wave staging 1xA + 2xB dma16, counted
//      vmcnt(3). Blocked-layout math: 64-aligned m0 stays in one
//      128-panel; unified Asrc formula handles both tile heights.
//  (2) ln_mod reduction: 8-barrier halving tree -> wave shfl_down + one
//      8-float LDS exchange + 1 barrier.
// Lessons held: GEMM counted-vmcnt pipeline (R11); attn single-buffered
// 25.6KB (R9/R12/R13 all lost vs it), raw v_exp + paired P-stores (R14),
// hoisted pointer-bump staging (R15). No XCD swizzle (R10 regression).
// Workspace: 48 MB + 48 KB.
//
// Blocked layout (bf16, inner-dim K): for row r, col k:
//   idx = (r>>7)*128*K + (k>>3)*1024 + (r&127)*8 + (k&7)
// attn K per (b,h): idx = kb*4096 + (d>>3)*512 + (s&63)*8 + (d&7), kb=s>>6
// attn V per (b,h): PERMUTED rows sp = (s&32)|((s&15)<<1)|((s>>4)&1):
//   idx = kb*4096 + (sp>>3)*512 + d*8 + (sp&7)

typedef unsigned short u16;
typedef unsigned int   u32;
typedef __bf16 bf16x8 __attribute__((ext_vector_type(8)));
typedef float  f32x4  __attribute__((ext_vector_type(4)));

#define MFMA_BF16(a, b, c) __builtin_amdgcn_mfma_f32_16x16x32_bf16((a), (b), (c), 0, 0, 0)

__device__ __forceinline__ float b2f(u16 u) {
    union { u32 i; float f; } v; v.i = ((u32)u) << 16; return v.f;
}
__device__ __forceinline__ u16 f2b(float f) {
    union { u32 i; float f; } v; v.f = f;
    u32 i = v.i;
    return (u16)((i + 0x7FFFu + ((i >> 16) & 1u)) >> 16);  // RNE
}
// packed f32x2 -> bf16x2 (low = a, high = b)
__device__ __forceinline__ u32 pk2(float a, float b) {
#if __has_builtin(__builtin_amdgcn_cvt_pk_bf16_f32)
    typedef __bf16 bf16x2_t __attribute__((ext_vector_type(2)));
    union { bf16x2_t v; u32 u; } cv;
    cv.v = __builtin_amdgcn_cvt_pk_bf16_f32(a, b);
    return cv.u;
#else
    return (u32)f2b(a) | ((u32)f2b(b) << 16);
#endif
}
// raw v_exp_f32 (2^x), no libcall wrapper
__device__ __forceinline__ float exp2_raw(float x) {
#if __has_builtin(__builtin_amdgcn_exp2f)
    return __builtin_amdgcn_exp2f(x);
#else
    float r;
    __asm("v_exp_f32 %0, %1" : "=v"(r) : "v"(x));
    return r;
#endif
}
__device__ __forceinline__ float finz(float v) {
    return __builtin_isfinite(v) ? v : 0.0f;
}
__device__ __forceinline__ void dma16(const void* g, void* l) {
    __builtin_amdgcn_global_load_lds(
        (const __attribute__((address_space(1))) unsigned int*)(uintptr_t)g,
        (__attribute__((address_space(3))) unsigned int*)(uintptr_t)l,
        16, 0, 0);
}

// ---------------------------------------------------------------------------
// f32 -> bf16 blocked weight conversion. Thread i emits 8 contiguous u16 of
// the blocked output (one (row, kg) cell); reads 8 contiguous floats.
// ---------------------------------------------------------------------------
__global__ __launch_bounds__(256) void convert_kernel(
    const float* __restrict__ in, u16* __restrict__ out, int n8, int kshift)
{
    int i = blockIdx.x * 256 + threadIdx.x;
    if (i >= n8) return;
    size_t o = (size_t)i * 8;
    int bk   = (int)(o >> (kshift + 7));
    int rem  = (int)(o & (((size_t)128 << kshift) - 1));
    int kg   = rem >> 10;
    int nloc = (rem >> 3) & 127;
    const float* src = in + (((size_t)bk * 128 + nloc) << kshift) + kg * 8;
    float4 a = *(const float4*)src;
    float4 b = *(const float4*)(src + 4);
    union { u16 s[8]; float4 v; } wp;
    wp.s[0] = f2b(a.x); wp.s[1] = f2b(a.y); wp.s[2] = f2b(a.z); wp.s[3] = f2b(a.w);
    wp.s[4] = f2b(b.x); wp.s[5] = f2b(b.y); wp.s[6] = f2b(b.z); wp.s[7] = f2b(b.w);
    *(float4*)(out + o) = wp.v;
}

// ---------------------------------------------------------------------------
// mods = c @ ada_w.T + ada_b : (2, 6144), K=1024, f32. One wave per column.
// ---------------------------------------------------------------------------
__global__ __launch_bounds__(64) void mods_kernel(
    const float* __restrict__ c, const float* __restrict__ ada_w,
    const float* __restrict__ ada_b, float* __restrict__ mods)
{
    const int n = blockIdx.x;
    const int lane = threadIdx.x;
    const float* wr = ada_w + (size_t)n * 1024;
    float a0 = 0.f, a1 = 0.f;
    for (int k = lane; k < 1024; k += 64) {
        float w = wr[k];
        a0 += w * c[k];
        a1 += w * c[1024 + k];
    }
    for (int o = 32; o > 0; o >>= 1) {
        a0 += __shfl_down(a0, o, 64);
        a1 += __shfl_down(a1, o, 64);
    }
    if (lane == 0) {
        float bb = ada_b[n];
        mods[n]        = a0 + bb;
        mods[6144 + n] = a1 + bb;
    }
}

// ---------------------------------------------------------------------------
// LayerNorm + adaLN modulation. Input f32 (xf) or bf16 row-major (xbf).
// Output bf16 in BLOCKED layout (K=1024).
// R16: wave-shuffle reduction, single barrier (was 8-barrier halving tree).
// ---------------------------------------------------------------------------
__global__ __launch_bounds__(256) void ln_mod_kernel(
    const u16* __restrict__ xbf, const float* __restrict__ xf,
    const float* __restrict__ w, const float* __restrict__ mods,
    int scale_off, int shift_off, u16* __restrict__ out)
{
    const int row = blockIdx.x;          // b*2048 + s
    const int b   = row >> 11;
    const int tid = threadIdx.x;
    const int wave = tid >> 6, lane = tid & 63;
    const size_t base = (size_t)row * 1024 + tid * 4;
    float v[4];
    if (xf) {
        float4 t = *(const float4*)(xf + base);
        v[0] = t.x; v[1] = t.y; v[2] = t.z; v[3] = t.w;
    } else {
        uint2 p = *(const uint2*)(xbf + base);
        union { u32 i; float f; } a, bb, cc, d;
        a.i  = p.x << 16;          v[0] = a.f;
        bb.i = p.x & 0xFFFF0000u;  v[1] = bb.f;
        cc.i = p.y << 16;          v[2] = cc.f;
        d.i  = p.y & 0xFFFF0000u;  v[3] = d.f;
    }
    float s  = v[0] + v[1] + v[2] + v[3];
    float sq = v[0]*v[0] + v[1]*v[1] + v[2]*v[2] + v[3]*v[3];
    #pragma unroll
    for (int o = 32; o > 0; o >>= 1) {
        s  += __shfl_down(s,  o, 64);
        sq += __shfl_down(sq, o, 64);
    }
    __shared__ float ws[8];
    if (lane == 0) { ws[wave] = s; ws[4 + wave] = sq; }
    __syncthreads();
    const float ts = (ws[0] + ws[1]) + (ws[2] + ws[3]);
    const float tq = (ws[4] + ws[5]) + (ws[6] + ws[7]);
    const float mean = ts * (1.0f / 1024.0f);
    const float var  = tq * (1.0f / 1024.0f) - mean * mean;
    const float inv  = rsqrtf(fmaxf(var, 0.f) + 1e-5f);
    union { u16 s4[4]; uint2 u2; } pk;
    for (int i = 0; i < 4; ++i) {
        int cidx = tid * 4 + i;
        float y = (v[i] - mean) * inv * w[cidx];
        y = y * (1.0f + mods[b * 6144 + scale_off + cidx]) + mods[b * 6144 + shift_off + cidx];
        pk.s4[i] = f2b(y);
    }
    size_t o = ((size_t)(row >> 7)) * 131072 + ((tid * 4) >> 3) * 1024
             + (row & 127) * 8 + ((tid * 4) & 7);
    *(uint2*)(out + o) = pk.u2;
}

// ---------------------------------------------------------------------------
// m97-style GEMM on BLOCKED operands: C[M,N] = A[M,K] @ W[N,K]^T.
// TM x 128 tile (TM = 128 or 64), BK=32, 4 waves (2x2), each wave
// (TM/2)x64 output via [TM/32]x4 16x16x32 frags.
// R11 pipeline: 3-buffer LDS, depth-2 prefetch, counted vmcnt + raw
// s_barrier per K-step (T4); loads stay in flight across barriers; only
// the last iteration drains vmcnt(0). Per-wave loads/tile: TM/64 (A) + 2
// (B) -> vmcnt(4) for TM=128, vmcnt(3) for TM=64.
// R16: TM=64 for the N=1024 GEMMs -> grid 512 = 2 blocks/CU.
// MODE 1: +bias, exact GELU, BLOCKED bf16 out (fc1 -> mid, K'=4096)
// MODE 2: gate_msa*val + resid_f32, row-major bf16 out (out-proj -> x2)
// MODE 3: +bias, gate_mlp*val + resid_bf16(row-major), f32 out (fc2 -> d_out)
// MODE 4: fused RoPE; q (aux1) row-major (b,h,s,d) scaled by
//         hd^-0.5*log2(e); k (aux2) attn-K-blocked; v (out_bf) attn-V-
//         blocked with PERMUTED rows (matches attn's paired P layout).
// ---------------------------------------------------------------------------
template<int MODE, int TM>
__global__ __launch_bounds__(256) void gemm128(
    const u16* __restrict__ A, const u16* __restrict__ W,
    int M, int N, int K,
    const float* __restrict__ mods, const float* __restrict__ bias,
    const float* __restrict__ resid_f, const u16* __restrict__ resid_bf,
    float* __restrict__ out_f, u16* __restrict__ out_bf,
    u16* __restrict__ aux1, u16* __restrict__ aux2,
    const float* __restrict__ rcos, const float* __restrict__ rsin)
{
    constexpr int FI    = TM / 32;       // frags per wave in M
    constexpr int WROWS = TM / 2;        // rows per wave
    constexpr int ATILE = TM * 32;       // u16 per A K-step tile
    __shared__ u16 As[3][ATILE];
    __shared__ u16 Bs[3][4096];
    const int tid  = threadIdx.x;
    const int wave = tid >> 6, lane = tid & 63;
    const int quad = lane >> 4, l15 = lane & 15;
    const int wi = wave >> 1, wj = wave & 1;
    const int m0 = blockIdx.y * TM, n0 = blockIdx.x * 128;

    f32x4 acc[FI][4] = {};

    // unified blocked-A base: panel (m0>>7), row offset (m0&127) within it.
    const u16* Asrc = A + (size_t)(m0 >> 7) * 128 * K + (m0 & 127) * 8
                        + wave * 1024 + lane * 8;
    const u16* Bsrc = W + (size_t)n0 * K + wave * 1024 + lane * 8;

    // stage tile tt into LDS buffer buf (TM/64 + 2 loads per wave)
    auto stage = [&](int tt, int buf) {
        const u16* a = Asrc + (size_t)tt * 4096;
        const u16* b = Bsrc + (size_t)tt * 4096;
        if constexpr (TM == 128) {
            dma16(a,       &As[buf][wave * 1024]);
            dma16(a + 512, &As[buf][wave * 1024 + 512]);
        } else {
            dma16(a, &As[buf][wave * 512]);
        }
        dma16(b,       &Bs[buf][wave * 1024]);
        dma16(b + 512, &Bs[buf][wave * 1024 + 512]);
    };

    const int nt = K >> 5;           // >= 32 for all our shapes
    // prologue: tiles 0,1 into buffers 0,1
    stage(0, 0);
    stage(1, 1);

    int cur = 0;
    for (int t = 0; t < nt; ++t) {
        if (t + 1 < nt) {
            // own tile-t loads (all but newest tile's) complete
            if constexpr (TM == 128)
                __asm volatile("s_waitcnt vmcnt(4)" ::: "memory");
            else
                __asm volatile("s_waitcnt vmcnt(3)" ::: "memory");
        } else {
            __asm volatile("s_waitcnt vmcnt(0)" ::: "memory");
        }
        __builtin_amdgcn_s_barrier();   // no compiler-forced vmcnt(0) drain
        if (t + 2 < nt) {
            int nb = cur + 2; if (nb >= 3) nb -= 3;
            stage(t + 2, nb);
        }
        bf16x8 af[FI], bw[4];
        #pragma unroll
        for (int f = 0; f < FI; ++f)
            af[f] = *(const bf16x8*)(&As[cur][quad * (TM * 8) + (wi * WROWS + f * 16 + l15) * 8]);
        #pragma unroll
        for (int f = 0; f < 4; ++f)
            bw[f] = *(const bf16x8*)(&Bs[cur][quad * 1024 + (wj * 64 + f * 16 + l15) * 8]);
        #pragma unroll
        for (int fi = 0; fi < FI; ++fi)
            #pragma unroll
            for (int fj = 0; fj < 4; ++fj)
                acc[fi][fj] = MFMA_BF16(af[fi], bw[fj], acc[fi][fj]);
        cur = (cur + 1 == 3) ? 0 : cur + 1;
    }

    if (MODE == 4) {
        const int colbase = n0 + wj * 64;
        const int wcol = colbase >> 10;            // 0=q, 1=k, 2=v
        const int hh   = (colbase & 1023) >> 6;
        #pragma unroll
        for (int fi = 0; fi < FI; ++fi) {
            const int rbase = m0 + wi * WROWS + fi * 16 + quad * 4;
            #pragma unroll
            for (int reg = 0; reg < 4; ++reg) {
                const int r = rbase + reg;
                const int b = r >> 11, s = r & 2047;
                const int bh = b * 16 + hh;
                #pragma unroll
                for (int fj = 0; fj < 2; ++fj) {
                    const int d2 = fj * 16 + l15;
                    float va = acc[fi][fj][reg];
                    float vb = acc[fi][fj + 2][reg];
                    float ca = rcos[s * 64 + d2];
                    float sa = rsin[s * 64 + d2];
                    float ra = va * ca - vb * sa;     // out[d]
                    float rb = vb * ca + va * sa;     // out[d+32]
                    if (wcol == 0) {
                        // hd^-0.5 * log2(e): softmax uses raw v_exp (2^x)
                        ra *= 0.18033688011f; rb *= 0.18033688011f;
                        u16* dst = aux1 + ((size_t)bh * 2048 + s) * 64;
                        dst[d2]      = f2b(ra);
                        dst[d2 + 32] = f2b(rb);
                    } else if (wcol == 1) {
                        size_t base = (size_t)bh * 131072 + (s >> 6) * 4096
                                    + (s & 63) * 8 + (d2 & 7);
                        aux2[base + (d2 >> 3) * 512]        = f2b(ra);
                        aux2[base + ((d2 >> 3) + 4) * 512]  = f2b(rb);
                    } else {
                        // permuted row: matches attn's paired P-store layout
                        const int sl = s & 63;
                        const int sp = (sl & 32) | ((sl & 15) << 1) | ((sl >> 4) & 1);
                        size_t base = (size_t)bh * 131072 + (s >> 6) * 4096
                                    + (sp >> 3) * 512 + (sp & 7);
                        out_bf[base + d2 * 8]        = f2b(ra);
                        out_bf[base + (d2 + 32) * 8] = f2b(rb);
                    }
                }
            }
        }
        return;
    }

    #pragma unroll
    for (int fi = 0; fi < FI; ++fi) {
        #pragma unroll
        for (int fj = 0; fj < 4; ++fj) {
            const int cidx  = n0 + wj * 64 + fj * 16 + l15;
            const int rbase = m0 + wi * WROWS + fi * 16 + quad * 4;
            #pragma unroll
            for (int reg = 0; reg < 4; ++reg) {
                const int r = rbase + reg;
                float v = acc[fi][fj][reg];
                if (MODE == 1) {
                    float u = v + bias[cidx];
                    float g = 0.5f * u * (1.0f + erff(u * 0.70710678118654752f));
                    size_t o = ((size_t)(r >> 7)) * 524288 + (cidx >> 3) * 1024
                             + (r & 127) * 8 + (cidx & 7);
                    out_bf[o] = f2b(g);
                } else if (MODE == 2) {
                    int bb = r >> 11;
                    float gate = mods[bb * 6144 + 2048 + cidx];  // gate_msa
                    out_bf[(size_t)r * N + cidx] = f2b(gate * v + resid_f[(size_t)r * N + cidx]);
                } else if (MODE == 3) {
                    int bb = r >> 11;
                    float u = v + bias[cidx];
                    float gate = mods[bb * 6144 + 5120 + cidx];  // gate_mlp
                    out_f[(size_t)r * N + cidx] =
                        finz(gate * u + b2f(resid_bf[(size_t)r * N + cidx]));
                }
            }
        }
    }
}

// ---------------------------------------------------------------------------
// Flash attention, R15 (unchanged): R8 structure (single-buffer KV, 25.6KB
// LDS, 4 blocks/CU) + raw v_exp softmax (Q pre-scaled by log2 e), paired
// u32 P-stores (k-permutation matched by V rows), hoisted pointer-bump
// staging, deferred denominator.
// Block = (b,h, 64-query tile): 1024 blocks. 4 waves x 16 q.
// ---------------------------------------------------------------------------
__global__ __launch_bounds__(256, 4) void attn_kernel(
    const u16* __restrict__ Q, const u16* __restrict__ Kb,
    const u16* __restrict__ Vb, u16* __restrict__ O)
{
    __shared__ u16 Ks[4096];
    __shared__ u16 Vs[4096];
    __shared__ u16 Ps[4][16 * 72];
    const int tid  = threadIdx.x;
    const int wave = tid >> 6, lane = tid & 63;
    const int quad = lane >> 4, l15 = lane & 15;
    const int bh = blockIdx.x & 31, qt = blockIdx.x >> 5;

    const u16* Qh = Q + ((size_t)bh * 2048 + qt * 64) * 64;

    // hoisted staging bases: one pointer-bump per iteration, LDS dsts const
    const int soff = (2 * wave) * 512 + lane * 8;
    const u16* kSrc = Kb + (size_t)bh * 131072 + soff;
    const u16* vSrc = Vb + (size_t)bh * 131072 + soff;
    u16* kDst0 = &Ks[(2 * wave) * 512];
    u16* kDst1 = &Ks[(2 * wave + 1) * 512];
    u16* vDst0 = &Vs[(2 * wave) * 512];
    u16* vDst1 = &Vs[(2 * wave + 1) * 512];

    bf16x8 aq[2];
    #pragma unroll
    for (int kh = 0; kh < 2; ++kh)
        aq[kh] = *(const bf16x8*)(Qh + (size_t)(wave * 16 + l15) * 64 + kh * 32 + quad * 8);

    f32x4 acc_o[4] = {};
    float lsum[4] = {0.f, 0.f, 0.f, 0.f};

    for (int kb = 0; kb < 32; ++kb) {
        __syncthreads();
        dma16(kSrc,       kDst0);
        dma16(kSrc + 512, kDst1);
        dma16(vSrc,       vDst0);
        dma16(vSrc + 512, vDst1);
        kSrc += 4096; vSrc += 4096;
        __syncthreads();

        f32x4 sc[4] = {};
        #pragma unroll
        for (int kt = 0; kt < 4; ++kt)
            #pragma unroll
            for (int kh = 0; kh < 2; ++kh) {
                bf16x8 bk = *(const bf16x8*)(&Ks[(quad + kh * 4) * 512 + (kt * 16 + l15) * 8]);
                sc[kt] = MFMA_BF16(aq[kh], bk, sc[kt]);
            }

        // p = 2^s (Q carries log2 e); clamp is overflow/NaN safety only.
        #pragma unroll
        for (int kt = 0; kt < 4; ++kt)
            #pragma unroll
            for (int reg = 0; reg < 4; ++reg)
                sc[kt][reg] = exp2_raw(fminf(sc[kt][reg], 72.f));
        #pragma unroll
        for (int reg = 0; reg < 4; ++reg)
            lsum[reg] += (sc[0][reg] + sc[1][reg]) + (sc[2][reg] + sc[3][reg]);

        // P: C-layout -> A-layout via wave-private LDS, paired u32 stores.
        // u16 col c holds k = 16*(c&1) + (c>>1) per 32-block; V rows are
        // permuted identically at write time (MODE 4), so PV is exact.
        #pragma unroll
        for (int reg = 0; reg < 4; ++reg) {
            u32* prow = (u32*)(&Ps[wave][(quad * 4 + reg) * 72]);
            prow[l15]      = pk2(sc[0][reg], sc[1][reg]);
            prow[16 + l15] = pk2(sc[2][reg], sc[3][reg]);
        }
        __asm volatile("s_waitcnt lgkmcnt(0)" ::: "memory");

        bf16x8 ap0 = *(const bf16x8*)(&Ps[wave][l15 * 72 + quad * 8]);
        bf16x8 ap1 = *(const bf16x8*)(&Ps[wave][l15 * 72 + 32 + quad * 8]);
        #pragma unroll
        for (int dt = 0; dt < 4; ++dt) {
            bf16x8 bv0 = *(const bf16x8*)(&Vs[quad * 512 + (dt * 16 + l15) * 8]);
            bf16x8 bv1 = *(const bf16x8*)(&Vs[(quad + 4) * 512 + (dt * 16 + l15) * 8]);
            acc_o[dt] = MFMA_BF16(ap0, bv0, acc_o[dt]);
            acc_o[dt] = MFMA_BF16(ap1, bv1, acc_o[dt]);
        }
    }

    // deferred denominator: reduce partial sums across the 16 lanes of the quad
    float linv[4];
    #pragma unroll
    for (int reg = 0; reg < 4; ++reg) {
        float l = lsum[reg];
        l += __shfl_xor(l, 1, 64);
        l += __shfl_xor(l, 2, 64);
        l += __shfl_xor(l, 4, 64);
        l += __shfl_xor(l, 8, 64);
        linv[reg] = 1.0f / l;
    }

    // O write in GEMM-blocked layout (out-proj A-operand, K=1024)
    const int b = bh >> 4, hh = bh & 15;
    #pragma unroll
    for (int dt = 0; dt < 4; ++dt)
        #pragma unroll
        for (int reg = 0; reg < 4; ++reg) {
            int q = qt * 64 + wave * 16 + quad * 4 + reg;
            int r = b * 2048 + q;
            int col = hh * 64 + dt * 16 + l15;
            float v = acc_o[dt][reg] * linv[reg];
            O[((size_t)(r >> 7)) * 131072 + (col >> 3) * 1024
              + (r & 127) * 8 + (col & 7)] = f2b(v);
        }
}

// ---------------------------------------------------------------------------
extern "C" void kernel_launch(void* const* d_in, const int* in_sizes, int n_in,
                              void* d_out, int out_size, void* d_ws, size_t ws_size,
                              hipStream_t stream)
{
    const float* x     = (const float*)d_in[0];
    const float* rcos  = (const float*)d_in[1];
    const float* rsin  = (const float*)d_in[2];
    const float* c     = (const float*)d_in[3];
    const float* n1w   = (const float*)d_in[4];
    const float* qkvw  = (const float*)d_in[5];
    const float* outw  = (const float*)d_in[6];
    const float* n2w   = (const float*)d_in[7];
    const float* fc1w  = (const float*)d_in[8];
    const float* fc1b  = (const float*)d_in[9];
    const float* fc2w  = (const float*)d_in[10];
    const float* fc2b  = (const float*)d_in[11];
    const float* adaw  = (const float*)d_in[12];
    const float* adab  = (const float*)d_in[13];
    float* out = (float*)d_out;

    // Arena (48 MB + 48 KB): [mods 48K][W 8M][S1 8M][S2 8M][S3 8M][S4 16M]
    char* ws = (char*)d_ws;
    const size_t MB8 = (size_t)8 * 1024 * 1024;
    float* mods  = (float*)ws;
    u16*   W     = (u16*)(ws + 49152);
    char*  S1    = ws + 49152 + MB8;
    char*  S2    = S1 + MB8;

    u16* h    = (u16*)d_out;       // LN1 out, blocked
    u16* qs   = (u16*)S1;          // (b,h,s,d) row-major, pre-scaled
    u16* ks   = (u16*)S2;          // attn-K blocked
    u16* vT   = (u16*)(S2 + MB8);  // attn-V blocked (permuted rows)
    u16* ob   = (u16*)d_out;       // attn out, GEMM-blocked
    u16* x2   = (u16*)S1;          // bf16 residual, row-major
    u16* h2   = (u16*)d_out;       // LN2 out, blocked
    u16* mid  = (u16*)S2;          // 32 MB, blocked (K'=4096)

    mods_kernel<<<6144, 64, 0, stream>>>(c, adaw, adab, mods);
    ln_mod_kernel<<<4096, 256, 0, stream>>>(nullptr, x, n1w, mods, 1024, 0, h);
    // qkv (+fused RoPE scatter)
    convert_kernel<<<1536, 256, 0, stream>>>(qkvw, W, 393216, 10);
    gemm128<4, 128><<<dim3(24, 32), 256, 0, stream>>>(h, W, 4096, 3072, 1024,
        nullptr, nullptr, nullptr, nullptr, nullptr, vT, qs, ks, rcos, rsin);
    attn_kernel<<<1024, 256, 0, stream>>>(qs, ks, vT, ob);
    // x2 = gate_msa * (o @ out_w^T) + x   (64-row tiles: grid 512 = 2/CU)
    convert_kernel<<<512, 256, 0, stream>>>(outw, W, 131072, 10);
    gemm128<2, 64><<<dim3(8, 64), 256, 0, stream>>>(ob, W, 4096, 1024, 1024,
        mods, nullptr, x, nullptr, nullptr, x2, nullptr, nullptr, nullptr, nullptr);
    // h2 = LN(x2)*(1+scale_mlp)+shift_mlp
    ln_mod_kernel<<<4096, 256, 0, stream>>>(x2, nullptr, n2w, mods, 4096, 3072, h2);
    // mid = gelu(h2 @ fc1_w^T + fc1_b)
    convert_kernel<<<2048, 256, 0, stream>>>(fc1w, W, 524288, 10);
    gemm128<1, 128><<<dim3(32, 32), 256, 0, stream>>>(h2, W, 4096, 4096, 1024,
        nullptr, fc1b, nullptr, nullptr, nullptr, mid, nullptr, nullptr, nullptr, nullptr);
    // out = gate_mlp * (mid @ fc2_w^T + fc2_b) + x2  (64-row tiles)
    convert_kernel<<<2048, 256, 0, stream>>>(fc2w, W, 524288, 12);
    gemm128<3, 64><<<dim3(8, 64), 256, 0, stream>>>(mid, W, 4096, 1024, 4096,
        mods, fc2b, nullptr, x2, out, nullptr, nullptr, nullptr, nullptr, nullptr);
}